// Round 1
// baseline (2252.884 us; speedup 1.0000x reference)
//
#include <hip/hip_runtime.h>

#define N_NODES 100000
#define N_EDGES 1200000

// Workspace layout (bytes):
//   deg : [0, 400000)                100000 f32, padded to 400384
//   agg : [400384, 26000384)         100000*64 f32 (reused for both layers)
//   h1  : [26000384, 51600384)       100000*64 f32
#define DEG_OFF   0
#define AGG_OFF   400384
#define H1_OFF    26000384
#define AGG_BYTES (100000 * 64 * 4)

// One edge handled by 16 threads; thread c of an edge moves float4 chunk c
// (4 floats) from feat[src] row to agg[dst] row via atomics.
__global__ __launch_bounds__(256) void scatter_kernel(
    const float* __restrict__ feat,
    const int* __restrict__ src,
    const int* __restrict__ dst,
    float* __restrict__ agg,
    float* __restrict__ deg,   // non-null only for layer 1 (also counts degree)
    int n_edges)
{
    long long tid = (long long)blockIdx.x * blockDim.x + threadIdx.x;
    long long total = (long long)n_edges * 16;
    if (tid >= total) return;
    int e = (int)(tid >> 4);
    int c = (int)(tid & 15);
    int s = src[e];
    int d = dst[e];
    float4 v = ((const float4*)(feat + (size_t)s * 64))[c];
    float* base = agg + (size_t)d * 64 + (size_t)c * 4;
    atomicAdd(base + 0, v.x);
    atomicAdd(base + 1, v.y);
    atomicAdd(base + 2, v.z);
    atomicAdd(base + 3, v.w);
    if (deg != nullptr && c == 0) atomicAdd(deg + d, 1.0f);
}

// h1 = relu(x @ Ws + (agg/deg) @ Wn + b)   -- 64 -> 64
__global__ __launch_bounds__(256) void node_l1_kernel(
    const float* __restrict__ x,
    const float* __restrict__ agg,
    const float* __restrict__ deg,
    const float* __restrict__ Ws,
    const float* __restrict__ Wn,
    const float* __restrict__ b,
    float* __restrict__ h1)
{
    __shared__ float sWs[64 * 64];
    __shared__ float sWn[64 * 64];
    __shared__ float sb[64];
    for (int i = threadIdx.x; i < 64 * 64; i += 256) {
        sWs[i] = Ws[i];
        sWn[i] = Wn[i];
    }
    if (threadIdx.x < 64) sb[threadIdx.x] = b[threadIdx.x];
    __syncthreads();

    int n = blockIdx.x * 256 + threadIdx.x;
    if (n >= N_NODES) return;

    float invd = 1.0f / fmaxf(deg[n], 1.0f);
    float xr[64], hr[64];
    const float4* xp = (const float4*)(x + (size_t)n * 64);
    const float4* ap = (const float4*)(agg + (size_t)n * 64);
#pragma unroll
    for (int k = 0; k < 16; k++) {
        float4 xv = xp[k];
        float4 av = ap[k];
        xr[4 * k + 0] = xv.x; xr[4 * k + 1] = xv.y;
        xr[4 * k + 2] = xv.z; xr[4 * k + 3] = xv.w;
        hr[4 * k + 0] = av.x * invd; hr[4 * k + 1] = av.y * invd;
        hr[4 * k + 2] = av.z * invd; hr[4 * k + 3] = av.w * invd;
    }

    float4* op = (float4*)(h1 + (size_t)n * 64);
#pragma unroll 1
    for (int j0 = 0; j0 < 64; j0 += 8) {
        float acc[8];
#pragma unroll
        for (int jj = 0; jj < 8; jj++) acc[jj] = sb[j0 + jj];
#pragma unroll
        for (int k = 0; k < 64; k++) {
            float xv = xr[k];
            float hv = hr[k];
#pragma unroll
            for (int jj = 0; jj < 8; jj++) {
                acc[jj] += xv * sWs[k * 64 + j0 + jj];
                acc[jj] += hv * sWn[k * 64 + j0 + jj];
            }
        }
        float4 o0 = make_float4(fmaxf(acc[0], 0.f), fmaxf(acc[1], 0.f),
                                fmaxf(acc[2], 0.f), fmaxf(acc[3], 0.f));
        float4 o1 = make_float4(fmaxf(acc[4], 0.f), fmaxf(acc[5], 0.f),
                                fmaxf(acc[6], 0.f), fmaxf(acc[7], 0.f));
        op[j0 / 4 + 0] = o0;
        op[j0 / 4 + 1] = o1;
    }
}

// out = h1 @ Ws + (agg/deg) @ Wn + b   -- 64 -> 16, no relu
__global__ __launch_bounds__(256) void node_l2_kernel(
    const float* __restrict__ h1,
    const float* __restrict__ agg,
    const float* __restrict__ deg,
    const float* __restrict__ Ws,   // [64,16]
    const float* __restrict__ Wn,   // [64,16]
    const float* __restrict__ b,    // [16]
    float* __restrict__ out)
{
    __shared__ float sWs[64 * 16];
    __shared__ float sWn[64 * 16];
    __shared__ float sb[16];
    for (int i = threadIdx.x; i < 64 * 16; i += 256) {
        sWs[i] = Ws[i];
        sWn[i] = Wn[i];
    }
    if (threadIdx.x < 16) sb[threadIdx.x] = b[threadIdx.x];
    __syncthreads();

    int n = blockIdx.x * 256 + threadIdx.x;
    if (n >= N_NODES) return;

    float invd = 1.0f / fmaxf(deg[n], 1.0f);
    float acc[16];
#pragma unroll
    for (int j = 0; j < 16; j++) acc[j] = sb[j];

    const float4* xp = (const float4*)(h1 + (size_t)n * 64);
    const float4* ap = (const float4*)(agg + (size_t)n * 64);
#pragma unroll
    for (int k4 = 0; k4 < 16; k4++) {
        float4 xv = xp[k4];
        float4 av = ap[k4];
        float xs[4] = {xv.x, xv.y, xv.z, xv.w};
        float hs[4] = {av.x * invd, av.y * invd, av.z * invd, av.w * invd};
#pragma unroll
        for (int t = 0; t < 4; t++) {
            int k = k4 * 4 + t;
#pragma unroll
            for (int j = 0; j < 16; j++) {
                acc[j] += xs[t] * sWs[k * 16 + j];
                acc[j] += hs[t] * sWn[k * 16 + j];
            }
        }
    }

    float4* op = (float4*)(out + (size_t)n * 16);
    op[0] = make_float4(acc[0], acc[1], acc[2], acc[3]);
    op[1] = make_float4(acc[4], acc[5], acc[6], acc[7]);
    op[2] = make_float4(acc[8], acc[9], acc[10], acc[11]);
    op[3] = make_float4(acc[12], acc[13], acc[14], acc[15]);
}

extern "C" void kernel_launch(void* const* d_in, const int* in_sizes, int n_in,
                              void* d_out, int out_size, void* d_ws, size_t ws_size,
                              hipStream_t stream) {
    const float* x   = (const float*)d_in[0];
    const int*   src = (const int*)d_in[1];
    const int*   dst = (const int*)d_in[2];
    const float* W1s = (const float*)d_in[3];
    const float* W1n = (const float*)d_in[4];
    const float* b1  = (const float*)d_in[5];
    const float* W2s = (const float*)d_in[6];
    const float* W2n = (const float*)d_in[7];
    const float* b2  = (const float*)d_in[8];
    float* out = (float*)d_out;

    char* ws = (char*)d_ws;
    float* deg = (float*)(ws + DEG_OFF);
    float* agg = (float*)(ws + AGG_OFF);
    float* h1  = (float*)(ws + H1_OFF);

    // zero deg + agg in one shot (contiguous)
    hipMemsetAsync(ws, 0, AGG_OFF + AGG_BYTES, stream);

    const int scatter_blocks = (int)(((long long)N_EDGES * 16 + 255) / 256);
    const int node_blocks = (N_NODES + 255) / 256;

    // Layer 1
    scatter_kernel<<<scatter_blocks, 256, 0, stream>>>(x, src, dst, agg, deg, N_EDGES);
    node_l1_kernel<<<node_blocks, 256, 0, stream>>>(x, agg, deg, W1s, W1n, b1, h1);

    // Layer 2 (reuse agg)
    hipMemsetAsync(agg, 0, AGG_BYTES, stream);
    scatter_kernel<<<scatter_blocks, 256, 0, stream>>>(h1, src, dst, agg, nullptr, N_EDGES);
    node_l2_kernel<<<node_blocks, 256, 0, stream>>>(h1, agg, deg, W2s, W2n, b2, out);
}

// Round 2
// 856.831 us; speedup vs baseline: 2.6293x; 2.6293x over previous
//
#include <hip/hip_runtime.h>

#define N_NODES 100000
#define N_EDGES 1200000

// Workspace layout (bytes):
//   row_ptr : [0, 400896)           100001 int
//   fill    : [400896, 801280)      100000 int (counts during hist, cursors during fill)
//   blk     : [801280, 801792)      scan block sums (98 int)
//   sorted  : [801792, 5601792)     1200000 int (src indices grouped by dst)
//   h1      : [5601792, 31201792)   100000*64 f32
#define OFF_ROWPTR 0
#define OFF_FILL   400896
#define OFF_BLK    801280
#define OFF_SORTED 801792
#define OFF_H1     5601792

// ---- CSR build ----

__global__ __launch_bounds__(256) void hist_kernel(
    const int* __restrict__ dst, int* __restrict__ counts)
{
    int e = blockIdx.x * 256 + threadIdx.x;
    if (e < N_EDGES) atomicAdd(&counts[dst[e]], 1);
}

// Per-block inclusive scan (1024 elems), writes block-local EXCLUSIVE scan + block total.
__global__ __launch_bounds__(1024) void scan_blocks_kernel(
    const int* __restrict__ counts, int* __restrict__ row_ptr, int* __restrict__ blk_sums)
{
    __shared__ int s[1024];
    int i = blockIdx.x * 1024 + threadIdx.x;
    int v = (i < N_NODES) ? counts[i] : 0;
    s[threadIdx.x] = v;
    __syncthreads();
    for (int off = 1; off < 1024; off <<= 1) {
        int t = (threadIdx.x >= off) ? s[threadIdx.x - off] : 0;
        __syncthreads();
        s[threadIdx.x] += t;
        __syncthreads();
    }
    if (i < N_NODES) row_ptr[i] = s[threadIdx.x] - v;   // exclusive, block-local
    if (threadIdx.x == 1023) blk_sums[blockIdx.x] = s[1023];
}

// Scan the 98 block sums (exclusive), in place into blk_sums.
__global__ __launch_bounds__(128) void scan_tops_kernel(int* __restrict__ blk_sums, int nblk)
{
    __shared__ int s[128];
    int v = (threadIdx.x < nblk) ? blk_sums[threadIdx.x] : 0;
    s[threadIdx.x] = v;
    __syncthreads();
    for (int off = 1; off < 128; off <<= 1) {
        int t = (threadIdx.x >= off) ? s[threadIdx.x - off] : 0;
        __syncthreads();
        s[threadIdx.x] += t;
        __syncthreads();
    }
    if (threadIdx.x < nblk) blk_sums[threadIdx.x] = s[threadIdx.x] - v;  // exclusive
}

__global__ __launch_bounds__(256) void add_offsets_kernel(
    int* __restrict__ row_ptr, int* __restrict__ fill, const int* __restrict__ blk_sums)
{
    int i = blockIdx.x * 256 + threadIdx.x;
    if (i < N_NODES) {
        int r = row_ptr[i] + blk_sums[i >> 10];
        row_ptr[i] = r;
        fill[i] = r;
    }
    if (i == 0) row_ptr[N_NODES] = N_EDGES;
}

__global__ __launch_bounds__(256) void fill_kernel(
    const int* __restrict__ src, const int* __restrict__ dst,
    int* __restrict__ fill, int* __restrict__ sorted_src)
{
    int e = blockIdx.x * 256 + threadIdx.x;
    if (e < N_EDGES) {
        int pos = atomicAdd(&fill[dst[e]], 1);
        sorted_src[pos] = src[e];
    }
}

// ---- Fused SAGE layer: gather-mean + dense (self & neigh) + bias (+ relu) ----
// Block = 256 threads = 4 waves; one wave per node; lane = input feature index.
// Weight column j lives in registers of the thread computing output j.
template <int OUT_F, bool RELU>
__global__ __launch_bounds__(256) void sage_layer_kernel(
    const float* __restrict__ feat,       // [N,64]
    const int* __restrict__ row_ptr,
    const int* __restrict__ sorted_src,
    const float* __restrict__ Ws,         // [64, OUT_F]
    const float* __restrict__ Wn,         // [64, OUT_F]
    const float* __restrict__ b,          // [OUT_F]
    float* __restrict__ out)              // [N, OUT_F]
{
    __shared__ float sX[4][64];
    __shared__ float sA[4][64];
    const int w = threadIdx.x >> 6;
    const int lane = threadIdx.x & 63;
    const int n = blockIdx.x * 4 + w;     // grid = 25000 -> n < 100000 exact

    // Weight columns into registers (all lanes; for OUT_F=16 groups duplicate).
    const int j = lane & (OUT_F - 1);
    float ws_r[64], wn_r[64];
#pragma unroll
    for (int k = 0; k < 64; ++k) {
        ws_r[k] = Ws[k * OUT_F + j];
        wn_r[k] = Wn[k * OUT_F + j];
    }
    const float bj = b[j];

    // Phase A: gather-mean into LDS (wave-uniform edge walk, coalesced row reads)
    const int start = row_ptr[n];
    const int end   = row_ptr[n + 1];
    float acc = 0.f;
    for (int e = start; e < end; ++e) {
        int s = __builtin_amdgcn_readfirstlane(sorted_src[e]);
        acc += feat[(size_t)s * 64 + lane];
    }
    const float invd = 1.0f / (float)max(end - start, 1);
    sA[w][lane] = acc * invd;
    sX[w][lane] = feat[(size_t)n * 64 + lane];
    __syncthreads();

    // Phase B: o_j = b_j + sum_k x_k*Ws[k][j] + a_k*Wn[k][j]
    float o = bj;
#pragma unroll
    for (int k = 0; k < 64; ++k) {
        o += sX[w][k] * ws_r[k] + sA[w][k] * wn_r[k];
    }
    if (RELU) o = fmaxf(o, 0.f);
    if (lane < OUT_F) out[(size_t)n * OUT_F + j] = o;
}

extern "C" void kernel_launch(void* const* d_in, const int* in_sizes, int n_in,
                              void* d_out, int out_size, void* d_ws, size_t ws_size,
                              hipStream_t stream) {
    const float* x   = (const float*)d_in[0];
    const int*   src = (const int*)d_in[1];
    const int*   dst = (const int*)d_in[2];
    const float* W1s = (const float*)d_in[3];
    const float* W1n = (const float*)d_in[4];
    const float* b1  = (const float*)d_in[5];
    const float* W2s = (const float*)d_in[6];
    const float* W2n = (const float*)d_in[7];
    const float* b2  = (const float*)d_in[8];
    float* out = (float*)d_out;

    char* ws = (char*)d_ws;
    int* row_ptr    = (int*)(ws + OFF_ROWPTR);
    int* fill       = (int*)(ws + OFF_FILL);
    int* blk_sums   = (int*)(ws + OFF_BLK);
    int* sorted_src = (int*)(ws + OFF_SORTED);
    float* h1       = (float*)(ws + OFF_H1);

    // zero the counts buffer (fill doubles as counts during hist)
    hipMemsetAsync(fill, 0, N_NODES * sizeof(int), stream);

    const int edge_blocks = (N_EDGES + 255) / 256;
    const int nscan_blocks = (N_NODES + 1023) / 1024;   // 98

    // CSR build (one graph, reused by both layers)
    hist_kernel<<<edge_blocks, 256, 0, stream>>>(dst, fill);
    scan_blocks_kernel<<<nscan_blocks, 1024, 0, stream>>>(fill, row_ptr, blk_sums);
    scan_tops_kernel<<<1, 128, 0, stream>>>(blk_sums, nscan_blocks);
    add_offsets_kernel<<<(N_NODES + 255) / 256, 256, 0, stream>>>(row_ptr, fill, blk_sums);
    fill_kernel<<<edge_blocks, 256, 0, stream>>>(src, dst, fill, sorted_src);

    // Fused layers
    sage_layer_kernel<64, true><<<N_NODES / 4, 256, 0, stream>>>(
        x, row_ptr, sorted_src, W1s, W1n, b1, h1);
    sage_layer_kernel<16, false><<<N_NODES / 4, 256, 0, stream>>>(
        h1, row_ptr, sorted_src, W2s, W2n, b2, out);
}

// Round 3
// 515.734 us; speedup vs baseline: 4.3683x; 1.6614x over previous
//
#include <hip/hip_runtime.h>

#define N_NODES 100000
#define N_EDGES 1200000

// Workspace layout (bytes):
//   row_ptr : [0, 400896)           100001 int
//   fill    : [400896, 801280)      100000 int (counts during hist, cursors during fill)
//   blk     : [801280, 801792)      scan block sums (98 int)
//   sorted  : [801792, 5601792)     1200000 int (src indices grouped by dst)
//   h1      : [5601792, 31201792)   100000*64 f32
#define OFF_ROWPTR 0
#define OFF_FILL   400896
#define OFF_BLK    801280
#define OFF_SORTED 801792
#define OFF_H1     5601792

// ---- CSR build ----

__global__ __launch_bounds__(256) void hist_kernel(
    const int* __restrict__ dst, int* __restrict__ counts)
{
    int e = blockIdx.x * 256 + threadIdx.x;
    if (e < N_EDGES) atomicAdd(&counts[dst[e]], 1);
}

__global__ __launch_bounds__(1024) void scan_blocks_kernel(
    const int* __restrict__ counts, int* __restrict__ row_ptr, int* __restrict__ blk_sums)
{
    __shared__ int s[1024];
    int i = blockIdx.x * 1024 + threadIdx.x;
    int v = (i < N_NODES) ? counts[i] : 0;
    s[threadIdx.x] = v;
    __syncthreads();
    for (int off = 1; off < 1024; off <<= 1) {
        int t = (threadIdx.x >= off) ? s[threadIdx.x - off] : 0;
        __syncthreads();
        s[threadIdx.x] += t;
        __syncthreads();
    }
    if (i < N_NODES) row_ptr[i] = s[threadIdx.x] - v;   // exclusive, block-local
    if (threadIdx.x == 1023) blk_sums[blockIdx.x] = s[1023];
}

__global__ __launch_bounds__(128) void scan_tops_kernel(int* __restrict__ blk_sums, int nblk)
{
    __shared__ int s[128];
    int v = (threadIdx.x < nblk) ? blk_sums[threadIdx.x] : 0;
    s[threadIdx.x] = v;
    __syncthreads();
    for (int off = 1; off < 128; off <<= 1) {
        int t = (threadIdx.x >= off) ? s[threadIdx.x - off] : 0;
        __syncthreads();
        s[threadIdx.x] += t;
        __syncthreads();
    }
    if (threadIdx.x < nblk) blk_sums[threadIdx.x] = s[threadIdx.x] - v;  // exclusive
}

__global__ __launch_bounds__(256) void add_offsets_kernel(
    int* __restrict__ row_ptr, int* __restrict__ fill, const int* __restrict__ blk_sums)
{
    int i = blockIdx.x * 256 + threadIdx.x;
    if (i < N_NODES) {
        int r = row_ptr[i] + blk_sums[i >> 10];
        row_ptr[i] = r;
        fill[i] = r;
    }
    if (i == 0) row_ptr[N_NODES] = N_EDGES;
}

__global__ __launch_bounds__(256) void fill_kernel(
    const int* __restrict__ src, const int* __restrict__ dst,
    int* __restrict__ fill, int* __restrict__ sorted_src)
{
    int e = blockIdx.x * 256 + threadIdx.x;
    if (e < N_EDGES) {
        int pos = atomicAdd(&fill[dst[e]], 1);
        sorted_src[pos] = src[e];
    }
}

// ---- Fused SAGE layer v2 ----
// Block = 4 waves, one node per wave per grid-stride iteration.
// Weights register-resident ONCE per wave (amortized over ~30 nodes).
// Gather: 4 lane-groups x 16 lanes; each lane fetches a float4 (16 B) of one of
// 4 edges concurrently -> 1 KB per wave instruction, 4 independent loads in flight.
template <int OUT_F, bool RELU>
__global__ __launch_bounds__(256) void sage_layer_kernel(
    const float* __restrict__ feat,       // [N,64]
    const int* __restrict__ row_ptr,
    const int* __restrict__ sorted_src,
    const float* __restrict__ Ws,         // [64, OUT_F]
    const float* __restrict__ Wn,         // [64, OUT_F]
    const float* __restrict__ b,          // [OUT_F]
    float* __restrict__ out)              // [N, OUT_F]
{
    __shared__ float sX[4][64];
    __shared__ float sA[4][64];
    const int w = threadIdx.x >> 6;
    const int lane = threadIdx.x & 63;
    const int j = lane & (OUT_F - 1);
    const int group = lane >> 4;          // 0..3
    const int fl = lane & 15;             // float4 chunk index

    // Weight column j into registers, once per wave (loop-invariant).
    float ws_r[64], wn_r[64];
#pragma unroll
    for (int k = 0; k < 64; ++k) {
        ws_r[k] = Ws[k * OUT_F + j];
        wn_r[k] = Wn[k * OUT_F + j];
    }
    const float bj = b[j];

    const int wave_id = blockIdx.x * 4 + w;
    const int n_waves = gridDim.x * 4;

    for (int n = wave_id; n < N_NODES; n += n_waves) {
        const int start = row_ptr[n];
        const int deg = row_ptr[n + 1] - start;

        // ---- Phase A: gather-sum, 4 edges concurrently ----
        float4 acc = make_float4(0.f, 0.f, 0.f, 0.f);
        for (int base = 0; base < deg; base += 64) {
            const int m = min(64, deg - base);
            int eid = 0;
            if (lane < m) eid = sorted_src[start + base + lane];
            for (int jj = 0; jj < m; jj += 4) {
                const int idx = jj + group;
                const int s = __shfl(eid, idx);
                if (idx < m) {
                    float4 v = ((const float4*)(feat + (size_t)s * 64))[fl];
                    acc.x += v.x; acc.y += v.y; acc.z += v.z; acc.w += v.w;
                }
            }
        }
        // combine the 4 lane-groups (lanes l, l^16, l^32, l^48)
        acc.x += __shfl_xor(acc.x, 16); acc.y += __shfl_xor(acc.y, 16);
        acc.z += __shfl_xor(acc.z, 16); acc.w += __shfl_xor(acc.w, 16);
        acc.x += __shfl_xor(acc.x, 32); acc.y += __shfl_xor(acc.y, 32);
        acc.z += __shfl_xor(acc.z, 32); acc.w += __shfl_xor(acc.w, 32);

        const float invd = 1.0f / (float)max(deg, 1);
        if (group == 0) {
            ((float4*)sA[w])[fl] = make_float4(acc.x * invd, acc.y * invd,
                                               acc.z * invd, acc.w * invd);
            ((float4*)sX[w])[fl] = ((const float4*)(feat + (size_t)n * 64))[fl];
        }
        // wave-private LDS: same-wave DS ops are ordered; no block barrier needed

        // ---- Phase B: o_j = b_j + sum_k x_k*Ws[k][j] + a_k*Wn[k][j] ----
        float o = bj;
#pragma unroll
        for (int k4 = 0; k4 < 16; ++k4) {
            float4 xv = ((const float4*)sX[w])[k4];   // broadcast ds_read_b128
            float4 av = ((const float4*)sA[w])[k4];
            o += xv.x * ws_r[4 * k4 + 0] + av.x * wn_r[4 * k4 + 0];
            o += xv.y * ws_r[4 * k4 + 1] + av.y * wn_r[4 * k4 + 1];
            o += xv.z * ws_r[4 * k4 + 2] + av.z * wn_r[4 * k4 + 2];
            o += xv.w * ws_r[4 * k4 + 3] + av.w * wn_r[4 * k4 + 3];
        }
        if (RELU) o = fmaxf(o, 0.f);
        if (lane < OUT_F) out[(size_t)n * OUT_F + j] = o;
    }
}

extern "C" void kernel_launch(void* const* d_in, const int* in_sizes, int n_in,
                              void* d_out, int out_size, void* d_ws, size_t ws_size,
                              hipStream_t stream) {
    const float* x   = (const float*)d_in[0];
    const int*   src = (const int*)d_in[1];
    const int*   dst = (const int*)d_in[2];
    const float* W1s = (const float*)d_in[3];
    const float* W1n = (const float*)d_in[4];
    const float* b1  = (const float*)d_in[5];
    const float* W2s = (const float*)d_in[6];
    const float* W2n = (const float*)d_in[7];
    const float* b2  = (const float*)d_in[8];
    float* out = (float*)d_out;

    char* ws = (char*)d_ws;
    int* row_ptr    = (int*)(ws + OFF_ROWPTR);
    int* fill       = (int*)(ws + OFF_FILL);
    int* blk_sums   = (int*)(ws + OFF_BLK);
    int* sorted_src = (int*)(ws + OFF_SORTED);
    float* h1       = (float*)(ws + OFF_H1);

    hipMemsetAsync(fill, 0, N_NODES * sizeof(int), stream);

    const int edge_blocks = (N_EDGES + 255) / 256;
    const int nscan_blocks = (N_NODES + 1023) / 1024;   // 98

    hist_kernel<<<edge_blocks, 256, 0, stream>>>(dst, fill);
    scan_blocks_kernel<<<nscan_blocks, 1024, 0, stream>>>(fill, row_ptr, blk_sums);
    scan_tops_kernel<<<1, 128, 0, stream>>>(blk_sums, nscan_blocks);
    add_offsets_kernel<<<(N_NODES + 255) / 256, 256, 0, stream>>>(row_ptr, fill, blk_sums);
    fill_kernel<<<edge_blocks, 256, 0, stream>>>(src, dst, fill, sorted_src);

    // Fused layers: 768 blocks = 3072 waves (~12 waves/CU at ~170 VGPR), grid-stride
    sage_layer_kernel<64, true><<<768, 256, 0, stream>>>(
        x, row_ptr, sorted_src, W1s, W1n, b1, h1);
    sage_layer_kernel<16, false><<<768, 256, 0, stream>>>(
        h1, row_ptr, sorted_src, W2s, W2n, b2, out);
}

// Round 4
// 364.956 us; speedup vs baseline: 6.1730x; 1.4131x over previous
//
#include <hip/hip_runtime.h>

#define N_NODES 100000
#define N_EDGES 1200000

// Workspace layout (bytes), total ~44.0 MB (<= 51.6 MB proven available):
//   row_ptr : [0, 400896)            100001 int
//   fill    : [400896, 801280)       100000 int (counts during hist, cursors during fill)
//   blk     : [801280, 801792)       scan block sums (98 int)
//   sorted  : [801792, 5601792)      1200000 int (src ids grouped by dst)
//   y1/y2   : [5601792, 18401792)    y1: bf16[100000*64] (12.8MB); reused as y2: f32[100000*16]
//   h1      : [18401792, 44001792)   f32[100000*64]; holds z1 then relu(z1+mean) in place
#define OFF_ROWPTR 0
#define OFF_FILL   400896
#define OFF_BLK    801280
#define OFF_SORTED 801792
#define OFF_Y1     5601792
#define OFF_H1     18401792

__device__ __forceinline__ unsigned short f2bf(float f) {
    unsigned u = __float_as_uint(f);
    unsigned r = (u + 0x7fffu + ((u >> 16) & 1u)) >> 16;   // RNE
    return (unsigned short)r;
}

// ---- CSR build ----

__global__ __launch_bounds__(256) void hist_kernel(
    const int* __restrict__ dst, int* __restrict__ counts)
{
    int e = blockIdx.x * 256 + threadIdx.x;
    if (e < N_EDGES) atomicAdd(&counts[dst[e]], 1);
}

__global__ __launch_bounds__(1024) void scan_blocks_kernel(
    const int* __restrict__ counts, int* __restrict__ row_ptr, int* __restrict__ blk_sums)
{
    __shared__ int s[1024];
    int i = blockIdx.x * 1024 + threadIdx.x;
    int v = (i < N_NODES) ? counts[i] : 0;
    s[threadIdx.x] = v;
    __syncthreads();
    for (int off = 1; off < 1024; off <<= 1) {
        int t = (threadIdx.x >= off) ? s[threadIdx.x - off] : 0;
        __syncthreads();
        s[threadIdx.x] += t;
        __syncthreads();
    }
    if (i < N_NODES) row_ptr[i] = s[threadIdx.x] - v;   // exclusive, block-local
    if (threadIdx.x == 1023) blk_sums[blockIdx.x] = s[1023];
}

__global__ __launch_bounds__(128) void scan_tops_kernel(int* __restrict__ blk_sums, int nblk)
{
    __shared__ int s[128];
    int v = (threadIdx.x < nblk) ? blk_sums[threadIdx.x] : 0;
    s[threadIdx.x] = v;
    __syncthreads();
    for (int off = 1; off < 128; off <<= 1) {
        int t = (threadIdx.x >= off) ? s[threadIdx.x - off] : 0;
        __syncthreads();
        s[threadIdx.x] += t;
        __syncthreads();
    }
    if (threadIdx.x < nblk) blk_sums[threadIdx.x] = s[threadIdx.x] - v;  // exclusive
}

__global__ __launch_bounds__(256) void add_offsets_kernel(
    int* __restrict__ row_ptr, int* __restrict__ fill, const int* __restrict__ blk_sums)
{
    int i = blockIdx.x * 256 + threadIdx.x;
    if (i < N_NODES) {
        int r = row_ptr[i] + blk_sums[i >> 10];
        row_ptr[i] = r;
        fill[i] = r;
    }
    if (i == 0) row_ptr[N_NODES] = N_EDGES;
}

__global__ __launch_bounds__(256) void fill_kernel(
    const int* __restrict__ src, const int* __restrict__ dst,
    int* __restrict__ fill, int* __restrict__ sorted_src)
{
    int e = blockIdx.x * 256 + threadIdx.x;
    if (e < N_EDGES) {
        int pos = atomicAdd(&fill[dst[e]], 1);
        sorted_src[pos] = src[e];
    }
}

// ---- Dense transforms (linearity: aggregate AFTER transform) ----

// y1 = x @ W1n  (bf16 out), z1 = x @ W1s + b1  (f32, written into h1 buffer)
__global__ __launch_bounds__(256) void dense1_kernel(
    const float* __restrict__ x,
    const float* __restrict__ Wn, const float* __restrict__ Ws,
    const float* __restrict__ b,
    unsigned short* __restrict__ y1, float* __restrict__ z1)
{
    __shared__ float sWn[64 * 64];
    __shared__ float sWs[64 * 64];
    __shared__ float sb[64];
    for (int i = threadIdx.x; i < 64 * 64; i += 256) { sWn[i] = Wn[i]; sWs[i] = Ws[i]; }
    if (threadIdx.x < 64) sb[threadIdx.x] = b[threadIdx.x];
    __syncthreads();

    int n = blockIdx.x * 256 + threadIdx.x;
    if (n >= N_NODES) return;

    float xr[64];
    const float4* xp = (const float4*)(x + (size_t)n * 64);
#pragma unroll
    for (int k4 = 0; k4 < 16; ++k4) {
        float4 v = xp[k4];
        xr[4 * k4 + 0] = v.x; xr[4 * k4 + 1] = v.y;
        xr[4 * k4 + 2] = v.z; xr[4 * k4 + 3] = v.w;
    }

    uint4* yp = (uint4*)(y1 + (size_t)n * 64);
    float4* zp = (float4*)(z1 + (size_t)n * 64);
#pragma unroll 1
    for (int j0 = 0; j0 < 64; j0 += 8) {
        float ay[8], az[8];
#pragma unroll
        for (int jj = 0; jj < 8; ++jj) { ay[jj] = 0.f; az[jj] = sb[j0 + jj]; }
#pragma unroll
        for (int k = 0; k < 64; ++k) {
            float xv = xr[k];
#pragma unroll
            for (int jj = 0; jj < 8; ++jj) {
                ay[jj] += xv * sWn[k * 64 + j0 + jj];
                az[jj] += xv * sWs[k * 64 + j0 + jj];
            }
        }
        uint4 pk;
        pk.x = (unsigned)f2bf(ay[0]) | ((unsigned)f2bf(ay[1]) << 16);
        pk.y = (unsigned)f2bf(ay[2]) | ((unsigned)f2bf(ay[3]) << 16);
        pk.z = (unsigned)f2bf(ay[4]) | ((unsigned)f2bf(ay[5]) << 16);
        pk.w = (unsigned)f2bf(ay[6]) | ((unsigned)f2bf(ay[7]) << 16);
        yp[j0 / 8] = pk;
        zp[j0 / 4 + 0] = make_float4(az[0], az[1], az[2], az[3]);
        zp[j0 / 4 + 1] = make_float4(az[4], az[5], az[6], az[7]);
    }
}

// y2 = h1 @ W2n (f32), z2 = h1 @ W2s + b2  written directly into d_out
__global__ __launch_bounds__(256) void dense2_kernel(
    const float* __restrict__ h1,
    const float* __restrict__ Wn, const float* __restrict__ Ws,
    const float* __restrict__ b,
    float* __restrict__ y2, float* __restrict__ out)
{
    __shared__ float sWn[64 * 16];
    __shared__ float sWs[64 * 16];
    __shared__ float sb[16];
    for (int i = threadIdx.x; i < 64 * 16; i += 256) { sWn[i] = Wn[i]; sWs[i] = Ws[i]; }
    if (threadIdx.x < 16) sb[threadIdx.x] = b[threadIdx.x];
    __syncthreads();

    int n = blockIdx.x * 256 + threadIdx.x;
    if (n >= N_NODES) return;

    float hr[64];
    const float4* hp = (const float4*)(h1 + (size_t)n * 64);
#pragma unroll
    for (int k4 = 0; k4 < 16; ++k4) {
        float4 v = hp[k4];
        hr[4 * k4 + 0] = v.x; hr[4 * k4 + 1] = v.y;
        hr[4 * k4 + 2] = v.z; hr[4 * k4 + 3] = v.w;
    }

    float ay[16], az[16];
#pragma unroll
    for (int j = 0; j < 16; ++j) { ay[j] = 0.f; az[j] = sb[j]; }
#pragma unroll
    for (int k = 0; k < 64; ++k) {
        float hv = hr[k];
#pragma unroll
        for (int j = 0; j < 16; ++j) {
            ay[j] += hv * sWn[k * 16 + j];
            az[j] += hv * sWs[k * 16 + j];
        }
    }
    float4* yp = (float4*)(y2 + (size_t)n * 16);
    float4* op = (float4*)(out + (size_t)n * 16);
#pragma unroll
    for (int q = 0; q < 4; ++q) {
        yp[q] = make_float4(ay[4 * q], ay[4 * q + 1], ay[4 * q + 2], ay[4 * q + 3]);
        op[q] = make_float4(az[4 * q], az[4 * q + 1], az[4 * q + 2], az[4 * q + 3]);
    }
}

// ---- Pure gathers (no weights -> low VGPR -> high occupancy) ----

// h1[n] = relu(h1[n] + mean(y1[src])), y1 bf16 rows of 64 (128 B)
// One wave per node. 4 lane-groups of 16; lane reads 8 B (4 bf16) of one edge row.
__global__ __launch_bounds__(256) void gather1_kernel(
    const unsigned short* __restrict__ y1,
    const int* __restrict__ row_ptr,
    const int* __restrict__ sorted_src,
    float* __restrict__ h1)
{
    const int w = threadIdx.x >> 6;
    const int lane = threadIdx.x & 63;
    const int n = blockIdx.x * 4 + w;          // grid 25000 -> exact
    const int group = lane >> 4;
    const int fl = lane & 15;

    const int start = row_ptr[n];
    const int deg = row_ptr[n + 1] - start;

    float a0 = 0.f, a1 = 0.f, a2 = 0.f, a3 = 0.f;
    for (int base = 0; base < deg; base += 64) {
        const int m = min(64, deg - base);
        int eid = 0;
        if (lane < m) eid = sorted_src[start + base + lane];
        for (int jj = 0; jj < m; jj += 4) {
            const int idx = jj + group;
            const int s = __shfl(eid, idx);
            if (idx < m) {
                uint2 raw = ((const uint2*)(y1 + (size_t)s * 64))[fl];
                a0 += __uint_as_float(raw.x << 16);
                a1 += __uint_as_float(raw.x & 0xffff0000u);
                a2 += __uint_as_float(raw.y << 16);
                a3 += __uint_as_float(raw.y & 0xffff0000u);
            }
        }
    }
    a0 += __shfl_xor(a0, 16); a1 += __shfl_xor(a1, 16);
    a2 += __shfl_xor(a2, 16); a3 += __shfl_xor(a3, 16);
    a0 += __shfl_xor(a0, 32); a1 += __shfl_xor(a1, 32);
    a2 += __shfl_xor(a2, 32); a3 += __shfl_xor(a3, 32);

    const float invd = 1.0f / (float)max(deg, 1);
    if (group == 0) {
        float4* hp = (float4*)(h1 + (size_t)n * 64);
        float4 z = hp[fl];
        hp[fl] = make_float4(fmaxf(z.x + a0 * invd, 0.f),
                             fmaxf(z.y + a1 * invd, 0.f),
                             fmaxf(z.z + a2 * invd, 0.f),
                             fmaxf(z.w + a3 * invd, 0.f));
    }
}

// out[n] += mean(y2[src]), y2 f32 rows of 16 (64 B). 16 lane-groups of 4;
// lane reads one float4 -> 16 edges in flight per wave instruction.
__global__ __launch_bounds__(256) void gather2_kernel(
    const float* __restrict__ y2,
    const int* __restrict__ row_ptr,
    const int* __restrict__ sorted_src,
    float* __restrict__ out)
{
    const int w = threadIdx.x >> 6;
    const int lane = threadIdx.x & 63;
    const int n = blockIdx.x * 4 + w;
    const int group = lane >> 2;
    const int fl = lane & 3;

    const int start = row_ptr[n];
    const int deg = row_ptr[n + 1] - start;

    float4 acc = make_float4(0.f, 0.f, 0.f, 0.f);
    for (int base = 0; base < deg; base += 64) {
        const int m = min(64, deg - base);
        int eid = 0;
        if (lane < m) eid = sorted_src[start + base + lane];
        for (int jj = 0; jj < m; jj += 16) {
            const int idx = jj + group;
            const int s = __shfl(eid, idx);
            if (idx < m) {
                float4 v = ((const float4*)(y2 + (size_t)s * 16))[fl];
                acc.x += v.x; acc.y += v.y; acc.z += v.z; acc.w += v.w;
            }
        }
    }
#pragma unroll
    for (int d = 4; d <= 32; d <<= 1) {
        acc.x += __shfl_xor(acc.x, d); acc.y += __shfl_xor(acc.y, d);
        acc.z += __shfl_xor(acc.z, d); acc.w += __shfl_xor(acc.w, d);
    }
    const float invd = 1.0f / (float)max(deg, 1);
    if (lane < 4) {
        float4* op = (float4*)(out + (size_t)n * 16);
        float4 z = op[fl];
        op[fl] = make_float4(z.x + acc.x * invd, z.y + acc.y * invd,
                             z.z + acc.z * invd, z.w + acc.w * invd);
    }
}

extern "C" void kernel_launch(void* const* d_in, const int* in_sizes, int n_in,
                              void* d_out, int out_size, void* d_ws, size_t ws_size,
                              hipStream_t stream) {
    const float* x   = (const float*)d_in[0];
    const int*   src = (const int*)d_in[1];
    const int*   dst = (const int*)d_in[2];
    const float* W1s = (const float*)d_in[3];
    const float* W1n = (const float*)d_in[4];
    const float* b1  = (const float*)d_in[5];
    const float* W2s = (const float*)d_in[6];
    const float* W2n = (const float*)d_in[7];
    const float* b2  = (const float*)d_in[8];
    float* out = (float*)d_out;

    char* ws = (char*)d_ws;
    int* row_ptr    = (int*)(ws + OFF_ROWPTR);
    int* fill       = (int*)(ws + OFF_FILL);
    int* blk_sums   = (int*)(ws + OFF_BLK);
    int* sorted_src = (int*)(ws + OFF_SORTED);
    unsigned short* y1 = (unsigned short*)(ws + OFF_Y1);
    float* y2       = (float*)(ws + OFF_Y1);   // reuses y1 space after gather1
    float* h1       = (float*)(ws + OFF_H1);

    hipMemsetAsync(fill, 0, N_NODES * sizeof(int), stream);

    const int edge_blocks = (N_EDGES + 255) / 256;
    const int nscan_blocks = (N_NODES + 1023) / 1024;   // 98
    const int node_blocks = (N_NODES + 255) / 256;      // 391
    const int wave_blocks = N_NODES / 4;                // 25000

    // CSR build
    hist_kernel<<<edge_blocks, 256, 0, stream>>>(dst, fill);
    scan_blocks_kernel<<<nscan_blocks, 1024, 0, stream>>>(fill, row_ptr, blk_sums);
    scan_tops_kernel<<<1, 128, 0, stream>>>(blk_sums, nscan_blocks);
    add_offsets_kernel<<<node_blocks, 256, 0, stream>>>(row_ptr, fill, blk_sums);
    fill_kernel<<<edge_blocks, 256, 0, stream>>>(src, dst, fill, sorted_src);

    // Layer 1: transform-then-aggregate
    dense1_kernel<<<node_blocks, 256, 0, stream>>>(x, W1n, W1s, b1, y1, h1);
    gather1_kernel<<<wave_blocks, 256, 0, stream>>>(y1, row_ptr, sorted_src, h1);

    // Layer 2
    dense2_kernel<<<node_blocks, 256, 0, stream>>>(h1, W2n, W2s, b2, y2, out);
    gather2_kernel<<<wave_blocks, 256, 0, stream>>>(y2, row_ptr, sorted_src, out);
}